// Round 13
// baseline (143.987 us; speedup 1.0000x reference)
//
#include <hip/hip_runtime.h>
#include <math.h>

#define SEQ 512
#define FDIM 64
#define D 8
#define NT 512
#define NP 64              // row quads per block: thread p owns rows {p+64u} of its half
#define NE 8               // t-eighths (wave-uniform: qt = tid>>6)
#define TE (SEQ / NE)      // 64 t-steps per eighth

typedef float v2f __attribute__((ext_vector_type(2)));

__global__ __launch_bounds__(NT, 4) void hybrid_attn_kernel(
    const float* __restrict__ state,    // [B,S,F]
    const float* __restrict__ proj_w,   // [F,D]
    const float* __restrict__ proj_b,   // [D]
    const float* __restrict__ rotation, // [D,D]
    const float* __restrict__ entangle, // [D,D]
    const float* __restrict__ w1,       // [D,32]
    const float* __restrict__ b1,       // [32]
    const float* __restrict__ w2,       // [32,16]
    const float* __restrict__ b2,       // [16]
    const float* __restrict__ w3,       // [16,1]
    const float* __restrict__ b3,       // [1]
    float* __restrict__ out)            // [B,S]
{
    // ~55 KB LDS -> 2 blocks/CU = 16 waves/CU = 4 waves/SIMD (round-11 occupancy,
    // round-12 R=4 instruction economy). Merge buffer = dead s_q (no extra LDS).
    __shared__ __align__(16) float s_proj[SEQ * D];   // 16 KB (V)
    __shared__ __align__(16) float s_k[SEQ * D];      // 16 KB
    __shared__ __align__(16) float s_q[256 * D];      // 8 KB (q; then merge scratch; then attn)
    __shared__ __align__(16) float s_mm[4 * NE * NP]; // 8 KB  ([u*8+qt][p] sampled maxes)
    __shared__ __align__(16) float s_pw[FDIM * D];    // 2 KB
    __shared__ float s_rot[D * D];
    __shared__ float s_ent[D * D];
    __shared__ float s_pb[D];
    __shared__ float s_w1[D * 32];
    __shared__ float s_b1[32];
    __shared__ float s_w2[32 * 16];
    __shared__ float s_b2[16];
    __shared__ float s_w3[16];
    __shared__ float s_b3[1];

    const int bb   = blockIdx.x;
    const int b    = bb >> 1;      // batch
    const int half = bb & 1;       // which 256 q-rows this block owns
    const int tid  = threadIdx.x;

    // ---- stage small weights into LDS ----
    if (tid < FDIM * D) s_pw[tid] = proj_w[tid];
    if (tid < D * D) {
        s_rot[tid] = rotation[tid];
        s_ent[tid] = entangle[tid];
    }
    if (tid < D)       s_pb[tid] = proj_b[tid];
    if (tid < D * 32)  s_w1[tid] = w1[tid];
    if (tid < 32)      s_b1[tid] = b1[tid];
    if (tid < 32 * 16) s_w2[tid] = w2[tid];
    if (tid < 16) { s_b2[tid] = b2[tid]; s_w3[tid] = w3[tid]; }
    if (tid == 0)      s_b3[0] = b3[0];
    __syncthreads();

    // ---- phase 1 (verified): one thread per row; proj,k -> LDS; own-half q -> LDS ----
    {
        const int r = tid;
        float pj[D];
        #pragma unroll
        for (int j = 0; j < D; j++) pj[j] = s_pb[j];

        const float4* srp = (const float4*)(state + ((size_t)b * SEQ + r) * FDIM);
        #pragma unroll
        for (int c = 0; c < FDIM / 4; c++) {
            float4 v = srp[c];
            float vs[4] = {v.x, v.y, v.z, v.w};
            #pragma unroll
            for (int e = 0; e < 4; e++) {
                #pragma unroll
                for (int j = 0; j < D; j++) pj[j] += vs[e] * s_pw[(c * 4 + e) * D + j];
            }
        }

        const float QS = 0.35355339059327373f;  // 1/sqrt(8) folded into q
        float qv[D], kv[D];
        #pragma unroll
        for (int j = 0; j < D; j++) {
            float aq = 0.f, ak = 0.f;
            #pragma unroll
            for (int i = 0; i < D; i++) {
                aq += pj[i] * s_rot[i * D + j];
                ak += pj[i] * s_ent[i * D + j];
            }
            qv[j] = aq * QS;
            kv[j] = ak;
        }

        float4* dp = (float4*)(s_proj + r * D);
        dp[0] = make_float4(pj[0], pj[1], pj[2], pj[3]);
        dp[1] = make_float4(pj[4], pj[5], pj[6], pj[7]);
        float4* dk = (float4*)(s_k + r * D);
        dk[0] = make_float4(kv[0], kv[1], kv[2], kv[3]);
        dk[1] = make_float4(kv[4], kv[5], kv[6], kv[7]);
        if ((r >> 8) == half) {
            float4* dq = (float4*)(s_q + (r & 255) * D);
            dq[0] = make_float4(qv[0], qv[1], qv[2], qv[3]);
            dq[1] = make_float4(qv[4], qv[5], qv[6], qv[7]);
        }
    }
    __syncthreads();

    // ---- phase 2: 4 rows/thread (p+64u), t-eighth qt (wave-uniform) ----
    const int p    = tid & (NP - 1);
    const int qt   = tid >> 6;          // 0..7, uniform per wave
    const int toff = qt * TE;

    v2f q[4][4];
    #pragma unroll
    for (int u = 0; u < 4; u++) {
        const float4* qp = (const float4*)(s_q + (p + NP * u) * D);
        float4 x0 = qp[0], x1 = qp[1];
        q[u][0] = (v2f){x0.x, x0.y}; q[u][1] = (v2f){x0.z, x0.w};
        q[u][2] = (v2f){x1.x, x1.y}; q[u][3] = (v2f){x1.z, x1.w};
    }

    const float* kp = s_k    + toff * D;
    const float* vp = s_proj + toff * D;

    // m-pass: stride-4 samples (16 per eighth; union = the SAME 128-sample set
    // as rounds 10-12) -> LDS exchange -> global per-row m. Verified recipe.
    float m[4] = {-1e30f, -1e30f, -1e30f, -1e30f};
    for (int i = 0; i < TE / 4; i++) {
        const float4* kt = (const float4*)(kp + (4 * i) * D);  // wave-uniform
        float4 ka = kt[0], kb = kt[1];
        v2f kk0 = (v2f){ka.x, ka.y}, kk1 = (v2f){ka.z, ka.w};
        v2f kk2 = (v2f){kb.x, kb.y}, kk3 = (v2f){kb.z, kb.w};
        #pragma unroll
        for (int u = 0; u < 4; u++) {
            v2f d = q[u][0] * kk0; d = q[u][1] * kk1 + d;
            d = q[u][2] * kk2 + d; d = q[u][3] * kk3 + d;
            m[u] = fmaxf(m[u], d.x + d.y);
        }
    }
    #pragma unroll
    for (int u = 0; u < 4; u++) s_mm[(u * NE + qt) * NP + p] = m[u];
    __syncthreads();
    float nm[4];
    #pragma unroll
    for (int u = 0; u < 4; u++) {
        float mu = s_mm[(u * NE + 0) * NP + p];
        #pragma unroll
        for (int w = 1; w < NE; w++) mu = fmaxf(mu, s_mm[(u * NE + w) * NP + p]);
        nm[u] = -mu;
    }

    // main pass: packed-fp32; nm folded into dot init; shared m -> plain sums.
    float l[4] = {0.f, 0.f, 0.f, 0.f};
    v2f acc[4][4];
    #pragma unroll
    for (int u = 0; u < 4; u++) {
        #pragma unroll
        for (int j = 0; j < 4; j++) acc[u][j] = (v2f){0.f, 0.f};
    }

    #pragma unroll 2
    for (int t = 0; t < TE; t++) {
        const float4* kt = (const float4*)(kp + t * D);  // wave-uniform -> broadcast
        float4 ka = kt[0], kb = kt[1];
        v2f kk0 = (v2f){ka.x, ka.y}, kk1 = (v2f){ka.z, ka.w};
        v2f kk2 = (v2f){kb.x, kb.y}, kk3 = (v2f){kb.z, kb.w};
        const float4* vt = (const float4*)(vp + t * D);
        float4 va = vt[0], vb = vt[1];
        v2f vv0 = (v2f){va.x, va.y}, vv1 = (v2f){va.z, va.w};
        v2f vv2 = (v2f){vb.x, vb.y}, vv3 = (v2f){vb.z, vb.w};

        float e[4];
        #pragma unroll
        for (int u = 0; u < 4; u++) {
            v2f d = (v2f){nm[u], 0.f};
            d = q[u][0] * kk0 + d; d = q[u][1] * kk1 + d;
            d = q[u][2] * kk2 + d; d = q[u][3] * kk3 + d;
            e[u] = __expf(d.x + d.y);
            l[u] += e[u];
        }
        #pragma unroll
        for (int u = 0; u < 4; u++) {
            v2f ev = (v2f){e[u], e[u]};
            acc[u][0] = ev * vv0 + acc[u][0]; acc[u][1] = ev * vv1 + acc[u][1];
            acc[u][2] = ev * vv2 + acc[u][2]; acc[u][3] = ev * vv3 + acc[u][3];
        }
    }
    __syncthreads();   // main pass done; s_q's q-content dead -> reuse as scratch

    // ---- 4 one-row merge rounds through s_q: acc[(NE-1)*NP][8] + l[(NE-1)*NP] ----
    float* const mrg_acc = s_q;                      // 7*64*8 = 3584 floats, f4-aligned
    float* const mrg_l   = s_q + (NE - 1) * NP * 8;  // +448 -> 4032 <= 4096
    #pragma unroll
    for (int u = 0; u < 4; u++) {
        if (qt > 0) {
            const int slot = (qt - 1) * NP + p;
            float4* dd = (float4*)(mrg_acc + slot * 8);
            dd[0] = make_float4(acc[u][0].x, acc[u][0].y, acc[u][1].x, acc[u][1].y);
            dd[1] = make_float4(acc[u][2].x, acc[u][2].y, acc[u][3].x, acc[u][3].y);
            mrg_l[slot] = l[u];
        }
        __syncthreads();
        if (qt == 0) {
            #pragma unroll
            for (int w = 0; w < NE - 1; w++) {
                const int slot = w * NP + p;
                const float4* ss = (const float4*)(mrg_acc + slot * 8);
                float4 u0 = ss[0], u1 = ss[1];
                acc[u][0] += (v2f){u0.x, u0.y}; acc[u][1] += (v2f){u0.z, u0.w};
                acc[u][2] += (v2f){u1.x, u1.y}; acc[u][3] += (v2f){u1.z, u1.w};
                l[u] += mrg_l[slot];
            }
        }
        __syncthreads();
    }

    // ---- qt==0 normalizes + stages attn into s_q; then 256-thread MLP ----
    float* const s_attn = s_q;
    if (qt == 0) {
        #pragma unroll
        for (int u = 0; u < 4; u++) {
            const float inv = 1.0f / l[u];
            float4* dd = (float4*)(s_attn + (p + NP * u) * D);
            dd[0] = make_float4(acc[u][0].x*inv, acc[u][0].y*inv, acc[u][1].x*inv, acc[u][1].y*inv);
            dd[1] = make_float4(acc[u][2].x*inv, acc[u][2].y*inv, acc[u][3].x*inv, acc[u][3].y*inv);
        }
    }
    __syncthreads();

    // ---- phase 3: MLP head d -> 32 -> 16 -> 1, one thread per owned row ----
    if (tid < 256) {
        const float4* ap = (const float4*)(s_attn + tid * D);
        float4 a0 = ap[0], a1 = ap[1];
        float attn[D] = {a0.x, a0.y, a0.z, a0.w, a1.x, a1.y, a1.z, a1.w};

        float h1[32];
        #pragma unroll
        for (int j = 0; j < 32; j++) {
            float a = s_b1[j];
            #pragma unroll
            for (int i = 0; i < D; i++) a += attn[i] * s_w1[i * 32 + j];
            h1[j] = fmaxf(a, 0.f);
        }
        float h2[16];
        #pragma unroll
        for (int j = 0; j < 16; j++) {
            float a = s_b2[j];
            #pragma unroll
            for (int i = 0; i < 32; i++) a += h1[i] * s_w2[i * 16 + j];
            h2[j] = fmaxf(a, 0.f);
        }
        float o = s_b3[0];
        #pragma unroll
        for (int i = 0; i < 16; i++) o += h2[i] * s_w3[i];

        out[(size_t)b * SEQ + half * 256 + tid] = o;
    }
}

extern "C" void kernel_launch(void* const* d_in, const int* in_sizes, int n_in,
                              void* d_out, int out_size, void* d_ws, size_t ws_size,
                              hipStream_t stream) {
    const float* state    = (const float*)d_in[0];
    const float* proj_w   = (const float*)d_in[1];
    const float* proj_b   = (const float*)d_in[2];
    const float* rotation = (const float*)d_in[3];
    const float* entangle = (const float*)d_in[4];
    const float* w1       = (const float*)d_in[5];
    const float* b1       = (const float*)d_in[6];
    const float* w2       = (const float*)d_in[7];
    const float* b2       = (const float*)d_in[8];
    const float* w3       = (const float*)d_in[9];
    const float* b3       = (const float*)d_in[10];
    float* out = (float*)d_out;

    const int B = in_sizes[0] / (SEQ * FDIM);  // 256
    hybrid_attn_kernel<<<B * 2, NT, 0, stream>>>(
        state, proj_w, proj_b, rotation, entangle,
        w1, b1, w2, b2, w3, b3, out);
}